// Round 1
// baseline (229.715 us; speedup 1.0000x reference)
//
#include <hip/hip_runtime.h>
#include <math.h>

#define TILE_R 32
#define TILE_C 64
#define XT_R 47          // TILE_R + 15
#define XT_C 84          // padded LDS stride (80 used cols); 84 -> all 32 banks hit
#define OW   2033        // output width/height = 2048 - 16 + 1
#define XDIM 2048

__global__ __launch_bounds__(256) void psnr_conv_kernel(
    const float* __restrict__ x,
    const float* __restrict__ kern,
    float* __restrict__ out)
{
    __shared__ float2 wb[4][256];                 // (w, -2*w*k_c) per tap
    __shared__ float  skk[4];                     // sum w*k_c^2
    __shared__ __align__(16) float xt[XT_R][XT_C];

    const int tid = threadIdx.x;

    // ---- per-block weight precompute (cheap one-off; avoids workspace) ----
    {
        float k0 = kern[tid];
        float k1 = kern[256 + tid];
        float k2 = kern[512 + tid];
        float k3 = kern[768 + tid];
        float a  = k3 * (1.0f / 255.0f);
        float om = 1.0f - a;
        float w  = om * om;
        wb[0][tid] = make_float2(w, -2.0f * w * k0);
        wb[1][tid] = make_float2(w, -2.0f * w * k1);
        wb[2][tid] = make_float2(w, -2.0f * w * k2);
        wb[3][tid] = make_float2(w, -2.0f * w * k3);

        float4* red = reinterpret_cast<float4*>(&xt[0][0]);  // reuse xt as scratch
        red[tid] = make_float4(w*k0*k0, w*k1*k1, w*k2*k2, w*k3*k3);
        __syncthreads();
        #pragma unroll
        for (int s = 128; s > 0; s >>= 1) {
            if (tid < s) {
                float4 o = red[tid + s];
                float4 m = red[tid];
                m.x += o.x; m.y += o.y; m.z += o.z; m.w += o.w;
                red[tid] = m;
            }
            __syncthreads();
        }
        if (tid == 0) {
            float4 r0 = red[0];
            skk[0] = r0.x; skk[1] = r0.y; skk[2] = r0.z; skk[3] = r0.w;
        }
        // barrier at top of channel loop covers readers
    }

    const int out_r0 = blockIdx.y * TILE_R;
    const int out_c0 = blockIdx.x * TILE_C;
    const int ty = tid >> 3;      // 0..31 : output row within tile
    const int tx = tid & 7;       // 0..7  : 8-col group within tile

    float psum[8];
    #pragma unroll
    for (int p = 0; p < 8; ++p) psum[p] = 0.0f;

    for (int c = 0; c < 4; ++c) {
        __syncthreads();          // previous users of xt done
        const float* __restrict__ xc = x + (size_t)c * XDIM * XDIM;

        // stage 47 x 80 tile as 20 float4 per row (clamped at borders;
        // clamped cells only feed outputs that are never stored)
        for (int i = tid; i < XT_R * 20; i += 256) {
            int r  = i / 20;
            int c4 = (i - r * 20) * 4;
            int gr = out_r0 + r; if (gr > XDIM - 1) gr = XDIM - 1;
            int gc = out_c0 + c4;
            const float* rp = xc + (size_t)gr * XDIM;
            float4 v;
            if (gc + 3 <= XDIM - 1) {
                v = *reinterpret_cast<const float4*>(rp + gc);
            } else {
                int c0 = gc     < XDIM ? gc     : XDIM - 1;
                int c1 = gc + 1 < XDIM ? gc + 1 : XDIM - 1;
                int c2 = gc + 2 < XDIM ? gc + 2 : XDIM - 1;
                int c3 = gc + 3 < XDIM ? gc + 3 : XDIM - 1;
                v = make_float4(rp[c0], rp[c1], rp[c2], rp[c3]);
            }
            *reinterpret_cast<float4*>(&xt[r][c4]) = v;
        }
        __syncthreads();

        float acc[8];
        #pragma unroll
        for (int p = 0; p < 8; ++p) acc[p] = 0.0f;

        for (int di = 0; di < 16; ++di) {
            // 24-wide register window of this thread's row
            float W[24];
            const float* row = &xt[ty + di][tx * 8];
            #pragma unroll
            for (int q = 0; q < 6; ++q) {
                float4 v = *reinterpret_cast<const float4*>(row + q * 4);
                W[q*4+0] = v.x; W[q*4+1] = v.y; W[q*4+2] = v.z; W[q*4+3] = v.w;
            }
            const float2* wrow = &wb[c][di * 16];
            #pragma unroll
            for (int dj = 0; dj < 16; ++dj) {
                float2 cb = wrow[dj];            // LDS broadcast (uniform addr)
                #pragma unroll
                for (int p = 0; p < 8; ++p) {
                    float xx = W[dj + p];
                    acc[p] = fmaf(xx, fmaf(cb.x, xx, cb.y), acc[p]);
                }
            }
        }

        float sk = skk[c];
        #pragma unroll
        for (int p = 0; p < 8; ++p) {
            float mse = (acc[p] + sk) * (1.0f / 256.0f);
            psum[p] += log10f(mse);
        }
    }

    // psnr = mean_c [20*log10(255) - 10*log10(mse_c)]
    //      = 20*log10(255) - 2.5 * sum_c log10(mse_c)
    const int orow = out_r0 + ty;
    const int ocol = out_c0 + tx * 8;
    if (orow < OW) {
        const float base = 20.0f * log10f(255.0f);
        float* orow_ptr = out + (size_t)orow * OW;
        #pragma unroll
        for (int p = 0; p < 8; ++p) {
            int oc = ocol + p;
            if (oc < OW) orow_ptr[oc] = base - 2.5f * psum[p];
        }
    }
}

extern "C" void kernel_launch(void* const* d_in, const int* in_sizes, int n_in,
                              void* d_out, int out_size, void* d_ws, size_t ws_size,
                              hipStream_t stream) {
    const float* x    = (const float*)d_in[0];
    const float* kern = (const float*)d_in[1];
    float* out        = (float*)d_out;

    dim3 grid((OW + TILE_C - 1) / TILE_C, (OW + TILE_R - 1) / TILE_R);  // 32 x 64
    psnr_conv_kernel<<<grid, 256, 0, stream>>>(x, kern, out);
}

// Round 2
// 70.615 us; speedup vs baseline: 3.2531x; 3.2531x over previous
//
#include <hip/hip_runtime.h>
#include <hip/hip_bf16.h>
#include <math.h>

#define XDIM 2048
#define OW   2033        // 2048 - 16 + 1
#define TR   32          // out rows per block tile
#define TC   256         // out cols per block tile
#define NIP  47          // i' iterations = TR + 15
#define XW   272         // staged pair-columns per image row (TC + 16)

typedef __bf16 bf16x8 __attribute__((ext_vector_type(8)));
typedef float  f32x16 __attribute__((ext_vector_type(16)));

union U128 { uint4 u; bf16x8 v; };

__device__ __forceinline__ unsigned short bfbits(float f) {
    return __builtin_bit_cast(unsigned short, __float2bfloat16(f));
}
// pair word: low16 = bf16(x^2) (plane p=0, weight w), high16 = bf16(x) (plane p=1, weight -2wk)
__device__ __forceinline__ unsigned int packx(float f) {
    return ((unsigned int)bfbits(f) << 16) | (unsigned int)bfbits(f * f);
}

__global__ __launch_bounds__(256) void psnr_mfma_kernel(
    const float* __restrict__ x,
    const float* __restrict__ kern,
    float* __restrict__ out)
{
    // X~ pairs for ONE channel: rows i'=0..46, cols 0..271 (16B-aligned rows not needed; word-granular reads)
    __shared__ __align__(16) unsigned int xt[NIP * XW];          // 51.1 KB
    // W~ tables: per channel, 17 rows (16 real + row16 = zeros), 20-word stride (80B, 16B-aligned)
    __shared__ __align__(16) unsigned int wt[4][17][20];          // 5.4 KB
    __shared__ float skkArr[4];

    const int tid  = threadIdx.x;
    const int lane = tid & 63;
    const int wv   = tid >> 6;         // wave 0..3
    const int nn   = lane & 31;        // = m for A-frags, n for B-frags, out-col offset
    const int hf   = lane >> 5;        // k-block half

    // ---------------- weight tables + Skk (once per block) ----------------
    {
        float k0 = kern[tid], k1 = kern[256 + tid], k2 = kern[512 + tid], k3 = kern[768 + tid];
        float a  = k3 * (1.0f / 255.0f);
        float om = 1.0f - a;
        float w  = om * om;
        int i = tid >> 4, j = tid & 15;
        unsigned int wlo = (unsigned int)bfbits(w);
        wt[0][i][j] = ((unsigned int)bfbits(-2.0f * w * k0) << 16) | wlo;
        wt[1][i][j] = ((unsigned int)bfbits(-2.0f * w * k1) << 16) | wlo;
        wt[2][i][j] = ((unsigned int)bfbits(-2.0f * w * k2) << 16) | wlo;
        wt[3][i][j] = ((unsigned int)bfbits(-2.0f * w * k3) << 16) | wlo;
        if (tid < 80) {                       // zero row 16 of each channel table
            int c = tid / 20, wd = tid % 20;
            wt[c][16][wd] = 0u;
        }
        // Skk_c = sum w*k_c^2  (fp32 tree reduction in xt scratch)
        float4* red = reinterpret_cast<float4*>(xt);
        red[tid] = make_float4(w*k0*k0, w*k1*k1, w*k2*k2, w*k3*k3);
        __syncthreads();
        #pragma unroll
        for (int s = 128; s > 0; s >>= 1) {
            if (tid < s) {
                float4 o = red[tid + s], m = red[tid];
                m.x += o.x; m.y += o.y; m.z += o.z; m.w += o.w;
                red[tid] = m;
            }
            __syncthreads();
        }
        if (tid == 0) {
            float4 r0v = red[0];
            skkArr[0] = r0v.x; skkArr[1] = r0v.y; skkArr[2] = r0v.z; skkArr[3] = r0v.w;
        }
    }

    const int r0 = blockIdx.y * TR;
    const int c0 = blockIdx.x * TC;

    f32x16 psum0 = {0.f}, psum1 = {0.f};
    #pragma unroll
    for (int q = 0; q < 16; ++q) { psum0[q] = 0.0f; psum1[q] = 0.0f; }

    for (int ch = 0; ch < 4; ++ch) {
        __syncthreads();                 // previous users of xt done (also covers wt/skk build)
        // ---------------- stage (x^2, x) bf16 pairs for this channel ----------------
        const float* __restrict__ xc = x + (size_t)ch * XDIM * XDIM;
        for (int idx = tid; idx < NIP * 68; idx += 256) {
            int row = idx / 68;
            int q4  = (idx - row * 68) * 4;          // pair col 0..268
            int gr  = r0 + row; if (gr > XDIM - 1) gr = XDIM - 1;
            int gc  = c0 + q4;
            const float* rp = xc + (size_t)gr * XDIM;
            float4 v;
            if (gc + 3 <= XDIM - 1) {
                v = *reinterpret_cast<const float4*>(rp + gc);
            } else {
                int e0 = gc     < XDIM ? gc     : XDIM - 1;
                int e1 = gc + 1 < XDIM ? gc + 1 : XDIM - 1;
                int e2 = gc + 2 < XDIM ? gc + 2 : XDIM - 1;
                int e3 = gc + 3 < XDIM ? gc + 3 : XDIM - 1;
                v = make_float4(rp[e0], rp[e1], rp[e2], rp[e3]);
            }
            uint4 pr;
            pr.x = packx(v.x); pr.y = packx(v.y); pr.z = packx(v.z); pr.w = packx(v.w);
            *reinterpret_cast<uint4*>(&xt[row * XW + q4]) = pr;
        }
        __syncthreads();

        // ---------------- MFMA i'-loop ----------------
        f32x16 acc0 = {0.f}, acc1 = {0.f};
        #pragma unroll
        for (int q = 0; q < 16; ++q) { acc0[q] = 0.0f; acc1[q] = 0.0f; }

        for (int ip = 0; ip < NIP; ++ip) {
            // A-frag: W~[i'-m, j], m = nn; invalid -> zero row 16
            unsigned int d = (unsigned int)(ip - nn);
            unsigned int wrow = (d > 15u) ? 16u : d;
            U128 alo, ahi;
            alo.u = *reinterpret_cast<const uint4*>(&wt[ch][wrow][hf * 4]);
            ahi.u = *reinterpret_cast<const uint4*>(&wt[ch][wrow][8 + hf * 4]);

            // B-frags: Hankel pair reads (word-granular -> 4x b32 each)
            int xb = ip * XW + nn + hf * 4 + (wv << 6);   // col group g = 2*wv
            U128 blo0, bhi0, blo1, bhi1;
            blo0.u = make_uint4(xt[xb],      xt[xb + 1],  xt[xb + 2],  xt[xb + 3]);
            bhi0.u = make_uint4(xt[xb + 8],  xt[xb + 9],  xt[xb + 10], xt[xb + 11]);
            blo1.u = make_uint4(xt[xb + 32], xt[xb + 33], xt[xb + 34], xt[xb + 35]);
            bhi1.u = make_uint4(xt[xb + 40], xt[xb + 41], xt[xb + 42], xt[xb + 43]);

            acc0 = __builtin_amdgcn_mfma_f32_32x32x16_bf16(alo.v, blo0.v, acc0, 0, 0, 0);
            acc0 = __builtin_amdgcn_mfma_f32_32x32x16_bf16(ahi.v, bhi0.v, acc0, 0, 0, 0);
            acc1 = __builtin_amdgcn_mfma_f32_32x32x16_bf16(alo.v, blo1.v, acc1, 0, 0, 0);
            acc1 = __builtin_amdgcn_mfma_f32_32x32x16_bf16(ahi.v, bhi1.v, acc1, 0, 0, 0);
        }

        // ---------------- per-channel epilogue: mse -> log10 accumulate ----------------
        float sk = skkArr[ch];
        #pragma unroll
        for (int q = 0; q < 16; ++q) {
            float m0 = (acc0[q] + sk) * (1.0f / 256.0f);
            float m1 = (acc1[q] + sk) * (1.0f / 256.0f);
            psum0[q] += log10f(m0);
            psum1[q] += log10f(m1);
        }
    }

    // ---------------- store: psnr = 20log10(255) - 2.5 * sum_c log10(mse_c) ----------------
    const float BASE = 48.130803608679344f;
    const int col0 = c0 + (wv << 6) + nn;      // col group 2*wv
    const int col1 = col0 + 32;                // col group 2*wv+1
    #pragma unroll
    for (int q = 0; q < 16; ++q) {
        int row = r0 + (q & 3) + ((q >> 2) << 3) + (hf << 2);
        if (row < OW) {
            float* orow = out + (size_t)row * OW;
            if (col0 < OW) orow[col0] = BASE - 2.5f * psum0[q];
            if (col1 < OW) orow[col1] = BASE - 2.5f * psum1[q];
        }
    }
}

extern "C" void kernel_launch(void* const* d_in, const int* in_sizes, int n_in,
                              void* d_out, int out_size, void* d_ws, size_t ws_size,
                              hipStream_t stream) {
    (void)in_sizes; (void)n_in; (void)d_ws; (void)ws_size; (void)out_size;
    const float* x    = (const float*)d_in[0];
    const float* kern = (const float*)d_in[1];
    float* out        = (float*)d_out;

    dim3 grid(XDIM / TC, (OW + TR - 1) / TR);   // 8 x 64 = 512 blocks
    psnr_mfma_kernel<<<grid, 256, 0, stream>>>(x, kern, out);
}